// Round 8
// baseline (489.742 us; speedup 1.0000x reference)
//
#include <hip/hip_runtime.h>
#include <stdint.h>

#define D_MODEL 2048
#define SEQ     2048
#define BATCH   2
#define NHEAD   16
#define HD      128
#define MROWS   (BATCH*SEQ)   // 4096

typedef short short8 __attribute__((ext_vector_type(8)));
typedef float f32x4  __attribute__((ext_vector_type(4)));

__device__ __forceinline__ unsigned short f2b(float f) {
  unsigned int u = __float_as_uint(f);
  u += 0x7fffu + ((u >> 16) & 1u);          // RNE
  return (unsigned short)(u >> 16);
}
__device__ __forceinline__ float b2f(unsigned short s) {
  return __uint_as_float(((unsigned int)s) << 16);
}
__device__ __forceinline__ void gll16(const void* g, void* l) {
  __builtin_amdgcn_global_load_lds((const __attribute__((address_space(1))) void*)g,
                                   (__attribute__((address_space(3))) void*)l, 16, 0, 0);
}
__device__ __forceinline__ void barrier_nodrain() {
  asm volatile("" ::: "memory");
  __builtin_amdgcn_s_barrier();
  asm volatile("" ::: "memory");
}
template<int N> __device__ __forceinline__ void vmwait() {
  if constexpr (N == 0)       asm volatile("s_waitcnt vmcnt(0)" ::: "memory");
  else if constexpr (N == 1)  asm volatile("s_waitcnt vmcnt(1)" ::: "memory");
  else if constexpr (N == 2)  asm volatile("s_waitcnt vmcnt(2)" ::: "memory");
  else if constexpr (N == 3)  asm volatile("s_waitcnt vmcnt(3)" ::: "memory");
  else if constexpr (N == 4)  asm volatile("s_waitcnt vmcnt(4)" ::: "memory");
  else if constexpr (N == 5)  asm volatile("s_waitcnt vmcnt(5)" ::: "memory");
  else if constexpr (N == 6)  asm volatile("s_waitcnt vmcnt(6)" ::: "memory");
  else if constexpr (N == 7)  asm volatile("s_waitcnt vmcnt(7)" ::: "memory");
  else if constexpr (N == 8)  asm volatile("s_waitcnt vmcnt(8)" ::: "memory");
  else if constexpr (N == 10) asm volatile("s_waitcnt vmcnt(10)" ::: "memory");
  else                        asm volatile("s_waitcnt vmcnt(12)" ::: "memory");
}

// ---------------- cast fp32 -> bf16 (x | Wq | Wk | Wv | Wo contiguous) ----------------
__global__ __launch_bounds__(256) void cast_all(
    const float* __restrict__ x,  const float* __restrict__ Wq,
    const float* __restrict__ Wk, const float* __restrict__ Wv,
    const float* __restrict__ Wo, unsigned short* __restrict__ dst)
{
  size_t e = ((size_t)blockIdx.x * 256 + threadIdx.x) * 4;
  const size_t XN = (size_t)MROWS * D_MODEL;   // 2^23
  const size_t WN = (size_t)D_MODEL * D_MODEL; // 2^22
  const float* src; size_t off;
  if (e < XN) { src = x; off = e; }
  else {
    size_t e2 = e - XN;
    int w = (int)(e2 >> 22);
    off = e2 & (WN - 1);
    src = (w == 0) ? Wq : (w == 1) ? Wk : (w == 2) ? Wv : Wo;
  }
  float4 v = *(const float4*)(src + off);
  ushort4 o;
  o.x = f2b(v.x); o.y = f2b(v.y); o.z = f2b(v.z); o.w = f2b(v.w);
  *(ushort4*)(dst + e) = o;
}

// ---------------- 2-merged-phase GEMM core: C = A @ B^T (r7, proven) ----------------
template<int BM, int LA>
__device__ __forceinline__ void gemm_2mp(
    const unsigned short* __restrict__ A, const unsigned short* __restrict__ Bw,
    unsigned short* __restrict__ As, unsigned short* __restrict__ Bs,
    int m0, int n0, int tid, f32x4 (&acc)[BM / 32][4])
{
  constexpr int K = D_MODEL, NT = K / 64;
  constexpr int HA = BM / 2;              // rows per A half
  constexpr int MI = BM / 32, MIH = MI / 2;
  constexpr int AHALF = HA * 64;          // elements per A half
  constexpr int BHALF = 128 * 64;
  constexpr int W1 = 2 * LA + 2;          // 6 @ LA=2
  constexpr int W2 = 2 * LA + 4;          // 8 @ LA=2
  const int wave = tid >> 6, lane = tid & 63, l15 = lane & 15, quad = lane >> 4;
  const int wr = wave >> 2, wc = wave & 3;
  const int rA = wr * 16 + l15;           // + ml*32 = row within A half
  const int rB = wc * 16 + l15;           // + nl*64 = row within B half
  const int swk = l15 & 7;                // read-side swizzle key (= rw&7)

  auto stA = [&](int buf, int h, int t) {
    #pragma unroll
    for (int i = 0; i < LA; ++i) {
      int slot = i * 512 + tid, rw = slot >> 3, ch = slot & 7;
      gll16(A + (size_t)(m0 + h * HA + rw) * K + t * 64 + ((ch ^ (rw & 7)) * 8),
            As + (buf * 2 + h) * AHALF + (i * 512 + wave * 64) * 8);
    }
  };
  auto stB = [&](int buf, int h, int t) {
    #pragma unroll
    for (int i = 0; i < 2; ++i) {
      int slot = i * 512 + tid, rw = slot >> 3, ch = slot & 7;
      gll16(Bw + (size_t)(n0 + h * 128 + rw) * K + t * 64 + ((ch ^ (rw & 7)) * 8),
            Bs + (buf * 2 + h) * BHALF + (i * 512 + wave * 64) * 8);
    }
  };
  auto ldA = [&](int buf, int h, int ml, int ks) -> short8 {
    int rw = ml * 32 + rA;
    return *(const short8*)(As + (buf * 2 + h) * AHALF + rw * 64 + (((ks * 4 + quad) ^ swk) * 8));
  };
  auto ldB = [&](int buf, int h, int nl, int ks) -> short8 {
    int rw = nl * 64 + rB;
    return *(const short8*)(Bs + (buf * 2 + h) * BHALF + rw * 64 + (((ks * 4 + quad) ^ swk) * 8));
  };

  // prologue, in steady-state age order: A0(0),B1(0) | B0(0),A1(0) | A0(1),B1(1)
  stA(0, 0, 0); stB(0, 1, 0);
  stB(0, 0, 0); stA(0, 1, 0);
  stA(1, 0, 1); stB(1, 1, 1);

  short8 ah[MIH][2], b0[2][2], b1[2][2];

  #pragma unroll 1
  for (int t = 0; t < NT; ++t) {
    const int buf = t & 1;

    // ---- MP1: quadrants (A0,B0) + (A0,B1), 32 MFMA ----
    if (t == NT - 1) vmwait<LA>(); else vmwait<W1>();
    barrier_nodrain();                     // A0(t),B0(t),B1(t) published (all waves)
    #pragma unroll
    for (int ml = 0; ml < MIH; ++ml) {
      ah[ml][0] = ldA(buf, 0, ml, 0); ah[ml][1] = ldA(buf, 0, ml, 1);
    }
    #pragma unroll
    for (int nl = 0; nl < 2; ++nl) {
      b0[nl][0] = ldB(buf, 0, nl, 0); b0[nl][1] = ldB(buf, 0, nl, 1);
      b1[nl][0] = ldB(buf, 1, nl, 0); b1[nl][1] = ldB(buf, 1, nl, 1);
    }
    if (t + 1 < NT) { stB(buf ^ 1, 0, t + 1); stA(buf ^ 1, 1, t + 1); }
    asm volatile("s_waitcnt lgkmcnt(0)" ::: "memory");
    __builtin_amdgcn_sched_barrier(0);
    __builtin_amdgcn_s_setprio(1);
    #pragma unroll
    for (int ml = 0; ml < MIH; ++ml)
      #pragma unroll
      for (int nl = 0; nl < 2; ++nl)
        #pragma unroll
        for (int ks = 0; ks < 2; ++ks)
          acc[ml][nl] = __builtin_amdgcn_mfma_f32_16x16x32_bf16(ah[ml][ks], b0[nl][ks], acc[ml][nl], 0, 0, 0);
    #pragma unroll
    for (int ml = 0; ml < MIH; ++ml)
      #pragma unroll
      for (int nl = 0; nl < 2; ++nl)
        #pragma unroll
        for (int ks = 0; ks < 2; ++ks)
          acc[ml][2 + nl] = __builtin_amdgcn_mfma_f32_16x16x32_bf16(ah[ml][ks], b1[nl][ks], acc[ml][2 + nl], 0, 0, 0);
    __builtin_amdgcn_s_setprio(0);

    // ---- MP2: quadrants (A1,B1) + (A1,B0), 32 MFMA ----
    if (t == NT - 1) vmwait<0>(); else vmwait<W2>();
    barrier_nodrain();                     // A1(t) published; MP1 reads done (WAR)
    #pragma unroll
    for (int ml = 0; ml < MIH; ++ml) {
      ah[ml][0] = ldA(buf, 1, ml, 0); ah[ml][1] = ldA(buf, 1, ml, 1);
    }
    if (t + 2 < NT) { stA(buf, 0, t + 2); stB(buf, 1, t + 2); }
    asm volatile("s_waitcnt lgkmcnt(0)" ::: "memory");
    __builtin_amdgcn_sched_barrier(0);
    __builtin_amdgcn_s_setprio(1);
    #pragma unroll
    for (int ml = 0; ml < MIH; ++ml)
      #pragma unroll
      for (int nl = 0; nl < 2; ++nl)
        #pragma unroll
        for (int ks = 0; ks < 2; ++ks)
          acc[MIH + ml][2 + nl] = __builtin_amdgcn_mfma_f32_16x16x32_bf16(ah[ml][ks], b1[nl][ks], acc[MIH + ml][2 + nl], 0, 0, 0);
    #pragma unroll
    for (int ml = 0; ml < MIH; ++ml)
      #pragma unroll
      for (int nl = 0; nl < 2; ++nl)
        #pragma unroll
        for (int ks = 0; ks < 2; ++ks)
          acc[MIH + ml][nl] = __builtin_amdgcn_mfma_f32_16x16x32_bf16(ah[ml][ks], b0[nl][ks], acc[MIH + ml][nl], 0, 0, 0);
    __builtin_amdgcn_s_setprio(0);
  }
}

// ---------------- r1 3-cluster pipelined GEMM core (proven; for gemm_out) ----------------
template<int BM, int BN>
__device__ __forceinline__ void gemm_pipe(
    const unsigned short* __restrict__ A, const unsigned short* __restrict__ Bw,
    unsigned short* __restrict__ As, unsigned short* __restrict__ Bs,
    int m0, int n0, int tid, f32x4 (&acc)[BM / 32][4])
{
  constexpr int K  = D_MODEL;
  constexpr int NT = K / 64;
  constexpr int LA = BM / 64, LB = BN / 64;
  constexpr int LT = LA + LB;
  constexpr int MI = BM / 32, MH = MI / 2;
  const int wave = tid >> 6, lane = tid & 63, l15 = lane & 15, quad = lane >> 4;
  const int wr = wave >> 2, wc = wave & 3;
  const int sw = l15 & 7;
  const int arow = wr * (BM / 2) + l15;
  const int brow = wc * (BN / 4) + l15;

  auto stage = [&](int buf, int t) {
    const int kt = t * 64;
    #pragma unroll
    for (int i = 0; i < LA; ++i) {
      int slot = i * 512 + tid;
      int row = slot >> 3, ch = slot & 7;
      gll16(A + (size_t)(m0 + row) * K + kt + ((ch ^ (row & 7)) * 8),
            As + (size_t)buf * (BM * 64) + (size_t)(i * 512 + wave * 64) * 8);
    }
    #pragma unroll
    for (int i = 0; i < LB; ++i) {
      int slot = i * 512 + tid;
      int row = slot >> 3, ch = slot & 7;
      gll16(Bw + (size_t)(n0 + row) * K + kt + ((ch ^ (row & 7)) * 8),
            Bs + (size_t)buf * (BN * 64) + (size_t)(i * 512 + wave * 64) * 8);
    }
  };

  stage(0, 0);
  stage(1, 1);

  short8 ah[MH][2], bf[4][2];

  #pragma unroll 1
  for (int t = 0; t < NT; ++t) {
    const int cur = t & 1;
    if (t < NT - 1) {
      if constexpr (LT == 8) vmwait<8>(); else vmwait<6>();
    } else {
      vmwait<0>();
    }
    barrier_nodrain();

    const unsigned short* as = As + cur * (BM * 64);
    const unsigned short* bs = Bs + cur * (BN * 64);

    #pragma unroll
    for (int mi = 0; mi < MH; ++mi)
      #pragma unroll
      for (int ks = 0; ks < 2; ++ks)
        ah[mi][ks] = *(const short8*)(as + (arow + mi * 16) * 64 + (((ks * 4 + quad) ^ sw) * 8));
    #pragma unroll
    for (int ni = 0; ni < 2; ++ni)
      #pragma unroll
      for (int ks = 0; ks < 2; ++ks)
        bf[ni][ks] = *(const short8*)(bs + (brow + ni * 16) * 64 + (((ks * 4 + quad) ^ sw) * 8));
    __builtin_amdgcn_s_setprio(1);
    #pragma unroll
    for (int mi = 0; mi < MH; ++mi)
      #pragma unroll
      for (int ni = 0; ni < 2; ++ni)
        #pragma unroll
        for (int ks = 0; ks < 2; ++ks)
          acc[mi][ni] = __builtin_amdgcn_mfma_f32_16x16x32_bf16(ah[mi][ks], bf[ni][ks], acc[mi][ni], 0, 0, 0);
    __builtin_amdgcn_s_setprio(0);

    #pragma unroll
    for (int ni = 2; ni < 4; ++ni)
      #pragma unroll
      for (int ks = 0; ks < 2; ++ks)
        bf[ni][ks] = *(const short8*)(bs + (brow + ni * 16) * 64 + (((ks * 4 + quad) ^ sw) * 8));
    __builtin_amdgcn_s_setprio(1);
    #pragma unroll
    for (int mi = 0; mi < MH; ++mi)
      #pragma unroll
      for (int ni = 2; ni < 4; ++ni)
        #pragma unroll
        for (int ks = 0; ks < 2; ++ks)
          acc[mi][ni] = __builtin_amdgcn_mfma_f32_16x16x32_bf16(ah[mi][ks], bf[ni][ks], acc[mi][ni], 0, 0, 0);
    __builtin_amdgcn_s_setprio(0);

    #pragma unroll
    for (int mi = 0; mi < MH; ++mi)
      #pragma unroll
      for (int ks = 0; ks < 2; ++ks)
        ah[mi][ks] = *(const short8*)(as + (arow + (mi + MH) * 16) * 64 + (((ks * 4 + quad) ^ sw) * 8));
    __builtin_amdgcn_s_setprio(1);
    #pragma unroll
    for (int mi = 0; mi < MH; ++mi)
      #pragma unroll
      for (int ni = 2; ni < 4; ++ni)
        #pragma unroll
        for (int ks = 0; ks < 2; ++ks)
          acc[mi + MH][ni] = __builtin_amdgcn_mfma_f32_16x16x32_bf16(ah[mi][ks], bf[ni][ks], acc[mi + MH][ni], 0, 0, 0);
    #pragma unroll
    for (int mi = 0; mi < MH; ++mi)
      #pragma unroll
      for (int ni = 0; ni < 2; ++ni)
        #pragma unroll
        for (int ks = 0; ks < 2; ++ks)
          acc[mi + MH][ni] = __builtin_amdgcn_mfma_f32_16x16x32_bf16(ah[mi][ks], bf[ni][ks], acc[mi + MH][ni], 0, 0, 0);
    __builtin_amdgcn_s_setprio(0);

    barrier_nodrain();
    if (t + 2 < NT) stage(cur, t + 2);
  }
}

// ------- QKV GEMM + fused RoPE epilogue: A[4096x2048] @ [Wq;Wk;Wv]^T, N=6144 -------
// RoPE pair (d even, d odd) sits on lanes (l15, l15^1): one shfl_xor(1) gives the
// partner value; angle = s * theta^(-2i/HD), i = d>>1 (lane-pair uniform).
// Applied pre-bf16-rounding (one fewer quantize step than the old rope_k pass).
__global__ __launch_bounds__(512, 2) void gemm_qkv4(
    const unsigned short* __restrict__ Axb, const unsigned short* __restrict__ Wqkv,
    unsigned short* __restrict__ Qh, unsigned short* __restrict__ Kh,
    unsigned short* __restrict__ Vt)
{
  __shared__ unsigned short As[2 * 2 * 128 * 64];   // 64 KB
  __shared__ unsigned short Bs[2 * 2 * 128 * 64];   // 64 KB
  const int m0 = blockIdx.y * 256, n0g = blockIdx.x * 256;   // no XCD swizzle (r5: +52% FETCH)
  f32x4 acc[8][4];
  #pragma unroll
  for (int i = 0; i < 8; ++i)
    #pragma unroll
    for (int j = 0; j < 4; ++j) acc[i][j] = (f32x4){0.f, 0.f, 0.f, 0.f};

  gemm_2mp<256, 2>(Axb, Wqkv, As, Bs, m0, n0g, threadIdx.x, acc);

  const int tid = threadIdx.x, wave = tid >> 6, lane = tid & 63;
  const int l15 = lane & 15, quad = lane >> 4, wr = wave >> 2, wc = wave & 3;
  const int z = n0g >> 11;                      // 0=Q 1=K 2=V (uniform per block)
  if (z < 2) {
    unsigned short* dst = z ? Kh : Qh;
    #pragma unroll
    for (int mi = 0; mi < 8; ++mi)
      #pragma unroll
      for (int ni = 0; ni < 4; ++ni) {
        int row0 = m0 + mi * 32 + wr * 16 + quad * 4;
        int col  = (n0g + ni * 64 + wc * 16 + l15) & (D_MODEL - 1);
        int h = col >> 7, d = col & (HD - 1);
        int i2 = d >> 1;
        float inv = exp2f(-(float)i2 * (13.287712379549449f / 64.0f));
        bool ev = (d & 1) == 0;
        #pragma unroll
        for (int r = 0; r < 4; ++r) {
          int m = row0 + r; int bb = m >> 11; int s = m & (SEQ - 1);
          float v  = acc[mi][ni][r];
          float vp = __shfl_xor(v, 1, 64);     // partner (d^1), same row
          float sn, cs; sincosf((float)s * inv, &sn, &cs);
          float ro = ev ? (v * cs - vp * sn) : (vp * sn + v * cs);
          dst[((size_t)(bb * NHEAD + h) * SEQ + s) * HD + d] = f2b(ro);
        }
      }
  } else {
    #pragma unroll
    for (int mi = 0; mi < 8; ++mi)
      #pragma unroll
      for (int ni = 0; ni < 4; ++ni) {
        int row0 = m0 + mi * 32 + wr * 16 + quad * 4;
        int col  = (n0g + ni * 64 + wc * 16 + l15) & (D_MODEL - 1);
        int h = col >> 7, d = col & (HD - 1);
        int bb = row0 >> 11; int s = row0 & (SEQ - 1);
        ushort4 pk;
        pk.x = f2b(acc[mi][ni][0]); pk.y = f2b(acc[mi][ni][1]);
        pk.z = f2b(acc[mi][ni][2]); pk.w = f2b(acc[mi][ni][3]);
        *(ushort4*)(Vt + ((size_t)(bb * NHEAD + h) * HD + d) * SEQ + s) = pk;
      }
  }
}

// ---------------- output GEMM: attn_out[4096x2048] @ Wo^T -> fp32 (r1 core) ----------------
__global__ __launch_bounds__(512, 2) void gemm_out2(
    const unsigned short* __restrict__ A, const unsigned short* __restrict__ Wo,
    float* __restrict__ C)
{
  __shared__ unsigned short As[2 * 128 * 64];   // 32 KB
  __shared__ unsigned short Bs[2 * 256 * 64];   // 64 KB
  const int m0 = blockIdx.y * 128, n0 = blockIdx.x * 256;    // no swizzle
  f32x4 acc[4][4];
  #pragma unroll
  for (int i = 0; i < 4; ++i)
    #pragma unroll
    for (int j = 0; j < 4; ++j) acc[i][j] = (f32x4){0.f, 0.f, 0.f, 0.f};

  gemm_pipe<128, 256>(A, Wo, As, Bs, m0, n0, threadIdx.x, acc);

  const int tid = threadIdx.x, wave = tid >> 6, lane = tid & 63;
  const int l15 = lane & 15, quad = lane >> 4, wr = wave >> 2, wc = wave & 3;
  #pragma unroll
  for (int mi = 0; mi < 4; ++mi)
    #pragma unroll
    for (int ni = 0; ni < 4; ++ni) {
      int row0 = m0 + wr * 64 + mi * 16 + quad * 4;
      int col  = n0 + wc * 64 + ni * 16 + l15;
      #pragma unroll
      for (int r = 0; r < 4; ++r)
        C[(size_t)(row0 + r) * D_MODEL + col] = acc[mi][ni][r];
    }
}

// ------- flash attention v5: paired q-tiles SHARE K/V staging -------
// Block x handles q-tiles {x, 31-x} in ONE k-loop of (32-x) staged tiles
// (was 33 in two passes): -26% staging traffic, fewer barriers, and up to
// 64 MFMA between barriers when both tiles are active. Per-q-row k-order
// and arithmetic identical to attn_k2.
__global__ __launch_bounds__(256) void attn_k3(
    const unsigned short* __restrict__ Qh, const unsigned short* __restrict__ Kh,
    const unsigned short* __restrict__ Vt, unsigned short* __restrict__ Aout)
{
  __shared__ unsigned short Ks[2][64 * 128];    // 32 KB, chunk' = chunk ^ (row&15)
  __shared__ unsigned short Vs[2][128 * 64];    // 32 KB, chunk' = chunk ^ (row&7)
  __shared__ unsigned short sPb[4][16 * 72];    // 9 KB, per-wave P, stride 72
  const int tid = threadIdx.x;
  const int wave = tid >> 6, lane = tid & 63, l15 = lane & 15, quad = lane >> 4;
  const int bh = blockIdx.y;
  const int b = bh >> 4, h = bh & 15;
  const unsigned short* Qb = Qh + (size_t)bh * SEQ * HD;
  const unsigned short* Kb = Kh + (size_t)bh * SEQ * HD;
  const unsigned short* Vb = Vt + (size_t)bh * HD * SEQ;
  unsigned short* pw = &sPb[wave][0];
  const float scl = 0.08838834764831845f * 1.4426950408889634f; // 1/sqrt(128)*log2(e)

  auto stageKV = [&](int bsel, int it) {
    const int k0s = it * 64;
    unsigned short* kd = &Ks[bsel][0];
    unsigned short* vd = &Vs[bsel][0];
    #pragma unroll
    for (int c = 0; c < 4; ++c) {       // K tile: 64 x 128
      int slot = c * 256 + tid;
      int kr = slot >> 4, pch = slot & 15;
      gll16(Kb + (size_t)(k0s + kr) * HD + ((pch ^ (kr & 15)) * 8), kd + slot * 8);
    }
    #pragma unroll
    for (int c = 0; c < 4; ++c) {       // V^T tile: 128 x 64
      int slot = c * 256 + tid;
      int vr = slot >> 3, pch = slot & 7;
      gll16(Vb + (size_t)vr * SEQ + k0s + ((pch ^ (vr & 7)) * 8), vd + slot * 8);
    }
  };

  const int tileA = blockIdx.x;          // 0..15
  const int tileB = 31 - blockIdx.x;     // 31..16
  const int tripsA = tileA + 1;          // 1..16
  const int ntrips = tileB + 1;          // 32..17 (loop length; B always active)
  const int q0wA = tileA * 64 + wave * 16, q0wB = tileB * 64 + wave * 16;
  const int qA = q0wA + l15, qB = q0wB + l15;

  short8 qfA[4], qfB[4];
  #pragma unroll
  for (int c = 0; c < 4; ++c) {
    qfA[c] = *(const short8*)(Qb + (size_t)(q0wA + l15) * HD + c * 32 + quad * 8);
    qfB[c] = *(const short8*)(Qb + (size_t)(q0wB + l15) * HD + c * 32 + quad * 8);
  }

  f32x4 oA[8], oB[8];
  #pragma unroll
  for (int dj = 0; dj < 8; ++dj) { oA[dj] = (f32x4){0.f,0.f,0.f,0.f}; oB[dj] = (f32x4){0.f,0.f,0.f,0.f}; }
  float msA = -1e30f, lsA = 0.f, msB = -1e30f, lsB = 0.f;

  stageKV(0, 0);
  vmwait<0>(); barrier_nodrain();        // tile 0 published

  // one q-tile's full update against the staged K/V tile (same math as attn_k2)
  auto process = [&](const short8 (&qf)[4], f32x4 (&o)[8], float& ms, float& ls,
                     int q0w, int q, const unsigned short* KsB,
                     const unsigned short* VsB, int k0) {
    f32x4 st[4];
    #pragma unroll
    for (int ni = 0; ni < 4; ++ni) st[ni] = (f32x4){0.f, 0.f, 0.f, 0.f};
    __builtin_amdgcn_s_setprio(1);
    #pragma unroll
    for (int ni = 0; ni < 4; ++ni) {
      const int rowb = (ni * 16 + l15) * 128;
      #pragma unroll
      for (int c = 0; c < 4; ++c) {
        short8 kf = *(const short8*)(KsB + rowb + (((c * 4 + quad) ^ l15) * 8));
        st[ni] = __builtin_amdgcn_mfma_f32_16x16x32_bf16(kf, qf[c], st[ni], 0, 0, 0);
      }
    }
    __builtin_amdgcn_s_setprio(0);

    if (k0 + 63 > q0w) {                 // causal mask near diagonal
      #pragma unroll
      for (int ni = 0; ni < 4; ++ni)
        #pragma unroll
        for (int r = 0; r < 4; ++r) {
          int k = k0 + ni * 16 + quad * 4 + r;
          if (k > q) st[ni][r] = -1e30f;
        }
    }

    float lm = -1e30f;
    #pragma unroll
    for (int ni = 0; ni < 4; ++ni)
      #pragma unroll
      for (int r = 0; r < 4; ++r) lm = fmaxf(lm, st[ni][r]);
    lm = fmaxf(lm, __shfl_xor(lm, 16, 64));
    lm = fmaxf(lm, __shfl_xor(lm, 32, 64));
    float mn = fmaxf(ms, lm);
    float al = exp2f((ms - mn) * scl);
    ms = mn;
    float nm = mn * scl;
    float rs = 0.f;
    #pragma unroll
    for (int ni = 0; ni < 4; ++ni)
      #pragma unroll
      for (int r = 0; r < 4; ++r) {
        float p = exp2f(fmaf(st[ni][r], scl, -nm));
        st[ni][r] = p;
        rs += p;
      }
    rs += __shfl_xor(rs, 16, 64);
    rs += __shfl_xor(rs, 32, 64);
    ls = ls * al + rs;
    #pragma unroll
    for (int dj = 0; dj < 8; ++dj) o[dj] *= al;

    #pragma unroll
    for (int ni = 0; ni < 4; ++ni) {
      ushort4 pk;
      pk.x = f2b(st[ni][0]); pk.y = f2b(st[ni][1]);
      pk.z = f2b(st[ni][2]); pk.w = f2b(st[ni][3]);
      *(ushort4*)(pw + l15 * 72 + ni * 16 + quad * 4) = pk;
    }
    short8 pf0 = *(const short8*)(pw + l15 * 72 + quad * 8);
    short8 pf1 = *(const short8*)(pw + l15 * 72 + 32 + quad * 8);

    __builtin_amdgcn_s_setprio(1);
    #pragma unroll
    for (int dj = 0; dj < 8; ++dj) {
      const int vrow = (dj * 16 + l15) * 64;
      short8 v0 = *(const short8*)(VsB + vrow + (((quad) ^ (l15 & 7)) * 8));
      short8 v1 = *(const short8*)(VsB + vrow + (((4 + quad) ^ (l15 & 7)) * 8));
      o[dj] = __builtin_amdgcn_mfma_f32_16x16x32_bf16(v0, pf0, o[dj], 0, 0, 0);
      o[dj] = __builtin_amdgcn_mfma_f32_16x16x32_bf16(v1, pf1, o[dj], 0, 0, 0);
    }
    __builtin_amdgcn_s_setprio(0);
  };

  for (int it = 0; it < ntrips; ++it) {
    const int cb = it & 1;
    const int k0 = it * 64;
    if (it + 1 < ntrips) stageKV(cb ^ 1, it + 1);   // prefetch next tile

    const unsigned short* KsB = &Ks[cb][0];
    const unsigned short* VsB = &Vs[cb][0];

    if (it < tripsA)                                 // block-uniform predicate
      process(qfA, oA, msA, lsA, q0wA, qA, KsB, VsB, k0);
    process(qfB, oB, msB, lsB, q0wB, qB, KsB, VsB, k0);

    vmwait<0>();          // own next-tile stages landed (issued before compute)
    barrier_nodrain();    // publish all waves' stages; reads of cb complete (WAR)
  }

  float rlA = 1.0f / lsA, rlB = 1.0f / lsB;
  #pragma unroll
  for (int dj = 0; dj < 8; ++dj) {
    ushort4 pa, pb;
    pa.x = f2b(oA[dj][0] * rlA); pa.y = f2b(oA[dj][1] * rlA);
    pa.z = f2b(oA[dj][2] * rlA); pa.w = f2b(oA[dj][3] * rlA);
    pb.x = f2b(oB[dj][0] * rlB); pb.y = f2b(oB[dj][1] * rlB);
    pb.z = f2b(oB[dj][2] * rlB); pb.w = f2b(oB[dj][3] * rlB);
    *(ushort4*)(Aout + ((size_t)(b * SEQ + qA)) * D_MODEL + h * HD + dj * 16 + quad * 4) = pa;
    *(ushort4*)(Aout + ((size_t)(b * SEQ + qB)) * D_MODEL + h * HD + dj * 16 + quad * 4) = pb;
  }
}

extern "C" void kernel_launch(void* const* d_in, const int* in_sizes, int n_in,
                              void* d_out, int out_size, void* d_ws, size_t ws_size,
                              hipStream_t stream)
{
  const float* x  = (const float*)d_in[0];
  const float* Wq = (const float*)d_in[1];
  const float* Wk = (const float*)d_in[2];
  const float* Wv = (const float*)d_in[3];
  const float* Wo = (const float*)d_in[4];
  float* out = (float*)d_out;

  unsigned short* xb  = (unsigned short*)d_ws;        // 8M
  unsigned short* wqb = xb  + 8388608;                // 4M each; Wq|Wk|Wv contiguous = stacked [6144][2048]
  unsigned short* wkb = wqb + 4194304;
  unsigned short* wvb = wkb + 4194304;
  unsigned short* wob = wvb + 4194304;
  unsigned short* qh  = wob + 4194304;                // 8M each
  unsigned short* kh  = qh  + 8388608;
  unsigned short* vt  = kh  + 8388608;
  unsigned short* ao  = vt  + 8388608;                // total 112 MB

  (void)wkb; (void)wvb;
  cast_all<<<24576, 256, 0, stream>>>(x, Wq, Wk, Wv, Wo, xb);
  gemm_qkv4<<<dim3(24, 16), 512, 0, stream>>>(xb, wqb, qh, kh, vt);
  attn_k3<<<dim3(16, 32), 256, 0, stream>>>(qh, kh, vt, ao);
  gemm_out2<<<dim3(8, 32), 512, 0, stream>>>(ao, wob, out);
}

// Round 9
// 382.207 us; speedup vs baseline: 1.2814x; 1.2814x over previous
//
#include <hip/hip_runtime.h>
#include <stdint.h>

#define D_MODEL 2048
#define SEQ     2048
#define BATCH   2
#define NHEAD   16
#define HD      128
#define MROWS   (BATCH*SEQ)   // 4096

typedef short short8 __attribute__((ext_vector_type(8)));
typedef float f32x4  __attribute__((ext_vector_type(4)));

__device__ __forceinline__ unsigned short f2b(float f) {
  unsigned int u = __float_as_uint(f);
  u += 0x7fffu + ((u >> 16) & 1u);          // RNE
  return (unsigned short)(u >> 16);
}
__device__ __forceinline__ float b2f(unsigned short s) {
  return __uint_as_float(((unsigned int)s) << 16);
}
__device__ __forceinline__ void gll16(const void* g, void* l) {
  __builtin_amdgcn_global_load_lds((const __attribute__((address_space(1))) void*)g,
                                   (__attribute__((address_space(3))) void*)l, 16, 0, 0);
}
__device__ __forceinline__ void barrier_nodrain() {
  asm volatile("" ::: "memory");
  __builtin_amdgcn_s_barrier();
  asm volatile("" ::: "memory");
}
template<int N> __device__ __forceinline__ void vmwait() {
  if constexpr (N == 0)       asm volatile("s_waitcnt vmcnt(0)" ::: "memory");
  else if constexpr (N == 1)  asm volatile("s_waitcnt vmcnt(1)" ::: "memory");
  else if constexpr (N == 2)  asm volatile("s_waitcnt vmcnt(2)" ::: "memory");
  else if constexpr (N == 3)  asm volatile("s_waitcnt vmcnt(3)" ::: "memory");
  else if constexpr (N == 4)  asm volatile("s_waitcnt vmcnt(4)" ::: "memory");
  else if constexpr (N == 5)  asm volatile("s_waitcnt vmcnt(5)" ::: "memory");
  else if constexpr (N == 6)  asm volatile("s_waitcnt vmcnt(6)" ::: "memory");
  else if constexpr (N == 7)  asm volatile("s_waitcnt vmcnt(7)" ::: "memory");
  else if constexpr (N == 8)  asm volatile("s_waitcnt vmcnt(8)" ::: "memory");
  else if constexpr (N == 10) asm volatile("s_waitcnt vmcnt(10)" ::: "memory");
  else                        asm volatile("s_waitcnt vmcnt(12)" ::: "memory");
}

// ---------------- cast fp32 -> bf16 (x | Wq | Wk | Wv | Wo contiguous) ----------------
__global__ __launch_bounds__(256) void cast_all(
    const float* __restrict__ x,  const float* __restrict__ Wq,
    const float* __restrict__ Wk, const float* __restrict__ Wv,
    const float* __restrict__ Wo, unsigned short* __restrict__ dst)
{
  size_t e = ((size_t)blockIdx.x * 256 + threadIdx.x) * 4;
  const size_t XN = (size_t)MROWS * D_MODEL;   // 2^23
  const size_t WN = (size_t)D_MODEL * D_MODEL; // 2^22
  const float* src; size_t off;
  if (e < XN) { src = x; off = e; }
  else {
    size_t e2 = e - XN;
    int w = (int)(e2 >> 22);
    off = e2 & (WN - 1);
    src = (w == 0) ? Wq : (w == 1) ? Wk : (w == 2) ? Wv : Wo;
  }
  float4 v = *(const float4*)(src + off);
  ushort4 o;
  o.x = f2b(v.x); o.y = f2b(v.y); o.z = f2b(v.z); o.w = f2b(v.w);
  *(ushort4*)(dst + e) = o;
}

// ---------------- RoPE cos/sin table: tab[s*64+i] = (cos, sin) of s*theta_i ----------------
// 2048 x 64 x 8B = 1 MB. sincosf lives HERE (tiny kernel), not in the GEMM epilogue
// (r8: sincosf in epilogue -> scratch round-trips, +196 MB HBM writes).
__global__ __launch_bounds__(256) void tab_k(float2* __restrict__ tab)
{
  int e = blockIdx.x * 256 + threadIdx.x;    // 131072 entries
  int s = e >> 6, i = e & 63;
  float inv = exp2f(-(float)i * (13.287712379549449f / 64.0f));
  float sn, cs; sincosf((float)s * inv, &sn, &cs);
  tab[e] = make_float2(cs, sn);
}

// ---------------- 2-merged-phase GEMM core: C = A @ B^T (r7, proven) ----------------
template<int BM, int LA>
__device__ __forceinline__ void gemm_2mp(
    const unsigned short* __restrict__ A, const unsigned short* __restrict__ Bw,
    unsigned short* __restrict__ As, unsigned short* __restrict__ Bs,
    int m0, int n0, int tid, f32x4 (&acc)[BM / 32][4])
{
  constexpr int K = D_MODEL, NT = K / 64;
  constexpr int HA = BM / 2;              // rows per A half
  constexpr int MI = BM / 32, MIH = MI / 2;
  constexpr int AHALF = HA * 64;          // elements per A half
  constexpr int BHALF = 128 * 64;
  constexpr int W1 = 2 * LA + 2;          // 6 @ LA=2
  constexpr int W2 = 2 * LA + 4;          // 8 @ LA=2
  const int wave = tid >> 6, lane = tid & 63, l15 = lane & 15, quad = lane >> 4;
  const int wr = wave >> 2, wc = wave & 3;
  const int rA = wr * 16 + l15;           // + ml*32 = row within A half
  const int rB = wc * 16 + l15;           // + nl*64 = row within B half
  const int swk = l15 & 7;                // read-side swizzle key (= rw&7)

  auto stA = [&](int buf, int h, int t) {
    #pragma unroll
    for (int i = 0; i < LA; ++i) {
      int slot = i * 512 + tid, rw = slot >> 3, ch = slot & 7;
      gll16(A + (size_t)(m0 + h * HA + rw) * K + t * 64 + ((ch ^ (rw & 7)) * 8),
            As + (buf * 2 + h) * AHALF + (i * 512 + wave * 64) * 8);
    }
  };
  auto stB = [&](int buf, int h, int t) {
    #pragma unroll
    for (int i = 0; i < 2; ++i) {
      int slot = i * 512 + tid, rw = slot >> 3, ch = slot & 7;
      gll16(Bw + (size_t)(n0 + h * 128 + rw) * K + t * 64 + ((ch ^ (rw & 7)) * 8),
            Bs + (buf * 2 + h) * BHALF + (i * 512 + wave * 64) * 8);
    }
  };
  auto ldA = [&](int buf, int h, int ml, int ks) -> short8 {
    int rw = ml * 32 + rA;
    return *(const short8*)(As + (buf * 2 + h) * AHALF + rw * 64 + (((ks * 4 + quad) ^ swk) * 8));
  };
  auto ldB = [&](int buf, int h, int nl, int ks) -> short8 {
    int rw = nl * 64 + rB;
    return *(const short8*)(Bs + (buf * 2 + h) * BHALF + rw * 64 + (((ks * 4 + quad) ^ swk) * 8));
  };

  // prologue, in steady-state age order: A0(0),B1(0) | B0(0),A1(0) | A0(1),B1(1)
  stA(0, 0, 0); stB(0, 1, 0);
  stB(0, 0, 0); stA(0, 1, 0);
  stA(1, 0, 1); stB(1, 1, 1);

  short8 ah[MIH][2], b0[2][2], b1[2][2];

  #pragma unroll 1
  for (int t = 0; t < NT; ++t) {
    const int buf = t & 1;

    // ---- MP1: quadrants (A0,B0) + (A0,B1), 32 MFMA ----
    if (t == NT - 1) vmwait<LA>(); else vmwait<W1>();
    barrier_nodrain();                     // A0(t),B0(t),B1(t) published (all waves)
    #pragma unroll
    for (int ml = 0; ml < MIH; ++ml) {
      ah[ml][0] = ldA(buf, 0, ml, 0); ah[ml][1] = ldA(buf, 0, ml, 1);
    }
    #pragma unroll
    for (int nl = 0; nl < 2; ++nl) {
      b0[nl][0] = ldB(buf, 0, nl, 0); b0[nl][1] = ldB(buf, 0, nl, 1);
      b1[nl][0] = ldB(buf, 1, nl, 0); b1[nl][1] = ldB(buf, 1, nl, 1);
    }
    if (t + 1 < NT) { stB(buf ^ 1, 0, t + 1); stA(buf ^ 1, 1, t + 1); }
    asm volatile("s_waitcnt lgkmcnt(0)" ::: "memory");
    __builtin_amdgcn_sched_barrier(0);
    __builtin_amdgcn_s_setprio(1);
    #pragma unroll
    for (int ml = 0; ml < MIH; ++ml)
      #pragma unroll
      for (int nl = 0; nl < 2; ++nl)
        #pragma unroll
        for (int ks = 0; ks < 2; ++ks)
          acc[ml][nl] = __builtin_amdgcn_mfma_f32_16x16x32_bf16(ah[ml][ks], b0[nl][ks], acc[ml][nl], 0, 0, 0);
    #pragma unroll
    for (int ml = 0; ml < MIH; ++ml)
      #pragma unroll
      for (int nl = 0; nl < 2; ++nl)
        #pragma unroll
        for (int ks = 0; ks < 2; ++ks)
          acc[ml][2 + nl] = __builtin_amdgcn_mfma_f32_16x16x32_bf16(ah[ml][ks], b1[nl][ks], acc[ml][2 + nl], 0, 0, 0);
    __builtin_amdgcn_s_setprio(0);

    // ---- MP2: quadrants (A1,B1) + (A1,B0), 32 MFMA ----
    if (t == NT - 1) vmwait<0>(); else vmwait<W2>();
    barrier_nodrain();                     // A1(t) published; MP1 reads done (WAR)
    #pragma unroll
    for (int ml = 0; ml < MIH; ++ml) {
      ah[ml][0] = ldA(buf, 1, ml, 0); ah[ml][1] = ldA(buf, 1, ml, 1);
    }
    if (t + 2 < NT) { stA(buf, 0, t + 2); stB(buf, 1, t + 2); }
    asm volatile("s_waitcnt lgkmcnt(0)" ::: "memory");
    __builtin_amdgcn_sched_barrier(0);
    __builtin_amdgcn_s_setprio(1);
    #pragma unroll
    for (int ml = 0; ml < MIH; ++ml)
      #pragma unroll
      for (int nl = 0; nl < 2; ++nl)
        #pragma unroll
        for (int ks = 0; ks < 2; ++ks)
          acc[MIH + ml][2 + nl] = __builtin_amdgcn_mfma_f32_16x16x32_bf16(ah[ml][ks], b1[nl][ks], acc[MIH + ml][2 + nl], 0, 0, 0);
    #pragma unroll
    for (int ml = 0; ml < MIH; ++ml)
      #pragma unroll
      for (int nl = 0; nl < 2; ++nl)
        #pragma unroll
        for (int ks = 0; ks < 2; ++ks)
          acc[MIH + ml][nl] = __builtin_amdgcn_mfma_f32_16x16x32_bf16(ah[ml][ks], b0[nl][ks], acc[MIH + ml][nl], 0, 0, 0);
    __builtin_amdgcn_s_setprio(0);
  }
}

// ---------------- r1 3-cluster pipelined GEMM core (proven; for gemm_out) ----------------
template<int BM, int BN>
__device__ __forceinline__ void gemm_pipe(
    const unsigned short* __restrict__ A, const unsigned short* __restrict__ Bw,
    unsigned short* __restrict__ As, unsigned short* __restrict__ Bs,
    int m0, int n0, int tid, f32x4 (&acc)[BM / 32][4])
{
  constexpr int K  = D_MODEL;
  constexpr int NT = K / 64;
  constexpr int LA = BM / 64, LB = BN / 64;
  constexpr int LT = LA + LB;
  constexpr int MI = BM / 32, MH = MI / 2;
  const int wave = tid >> 6, lane = tid & 63, l15 = lane & 15, quad = lane >> 4;
  const int wr = wave >> 2, wc = wave & 3;
  const int sw = l15 & 7;
  const int arow = wr * (BM / 2) + l15;
  const int brow = wc * (BN / 4) + l15;

  auto stage = [&](int buf, int t) {
    const int kt = t * 64;
    #pragma unroll
    for (int i = 0; i < LA; ++i) {
      int slot = i * 512 + tid;
      int row = slot >> 3, ch = slot & 7;
      gll16(A + (size_t)(m0 + row) * K + kt + ((ch ^ (row & 7)) * 8),
            As + (size_t)buf * (BM * 64) + (size_t)(i * 512 + wave * 64) * 8);
    }
    #pragma unroll
    for (int i = 0; i < LB; ++i) {
      int slot = i * 512 + tid;
      int row = slot >> 3, ch = slot & 7;
      gll16(Bw + (size_t)(n0 + row) * K + kt + ((ch ^ (row & 7)) * 8),
            Bs + (size_t)buf * (BN * 64) + (size_t)(i * 512 + wave * 64) * 8);
    }
  };

  stage(0, 0);
  stage(1, 1);

  short8 ah[MH][2], bf[4][2];

  #pragma unroll 1
  for (int t = 0; t < NT; ++t) {
    const int cur = t & 1;
    if (t < NT - 1) {
      if constexpr (LT == 8) vmwait<8>(); else vmwait<6>();
    } else {
      vmwait<0>();
    }
    barrier_nodrain();

    const unsigned short* as = As + cur * (BM * 64);
    const unsigned short* bs = Bs + cur * (BN * 64);

    #pragma unroll
    for (int mi = 0; mi < MH; ++mi)
      #pragma unroll
      for (int ks = 0; ks < 2; ++ks)
        ah[mi][ks] = *(const short8*)(as + (arow + mi * 16) * 64 + (((ks * 4 + quad) ^ sw) * 8));
    #pragma unroll
    for (int ni = 0; ni < 2; ++ni)
      #pragma unroll
      for (int ks = 0; ks < 2; ++ks)
        bf[ni][ks] = *(const short8*)(bs + (brow + ni * 16) * 64 + (((ks * 4 + quad) ^ sw) * 8));
    __builtin_amdgcn_s_setprio(1);
    #pragma unroll
    for (int mi = 0; mi < MH; ++mi)
      #pragma unroll
      for (int ni = 0; ni < 2; ++ni)
        #pragma unroll
        for (int ks = 0; ks < 2; ++ks)
          acc[mi][ni] = __builtin_amdgcn_mfma_f32_16x16x32_bf16(ah[mi][ks], bf[ni][ks], acc[mi][ni], 0, 0, 0);
    __builtin_amdgcn_s_setprio(0);

    #pragma unroll
    for (int ni = 2; ni < 4; ++ni)
      #pragma unroll
      for (int ks = 0; ks < 2; ++ks)
        bf[ni][ks] = *(const short8*)(bs + (brow + ni * 16) * 64 + (((ks * 4 + quad) ^ sw) * 8));
    __builtin_amdgcn_s_setprio(1);
    #pragma unroll
    for (int mi = 0; mi < MH; ++mi)
      #pragma unroll
      for (int ni = 2; ni < 4; ++ni)
        #pragma unroll
        for (int ks = 0; ks < 2; ++ks)
          acc[mi][ni] = __builtin_amdgcn_mfma_f32_16x16x32_bf16(ah[mi][ks], bf[ni][ks], acc[mi][ni], 0, 0, 0);
    __builtin_amdgcn_s_setprio(0);

    #pragma unroll
    for (int mi = 0; mi < MH; ++mi)
      #pragma unroll
      for (int ks = 0; ks < 2; ++ks)
        ah[mi][ks] = *(const short8*)(as + (arow + (mi + MH) * 16) * 64 + (((ks * 4 + quad) ^ sw) * 8));
    __builtin_amdgcn_s_setprio(1);
    #pragma unroll
    for (int mi = 0; mi < MH; ++mi)
      #pragma unroll
      for (int ni = 2; ni < 4; ++ni)
        #pragma unroll
        for (int ks = 0; ks < 2; ++ks)
          acc[mi + MH][ni] = __builtin_amdgcn_mfma_f32_16x16x32_bf16(ah[mi][ks], bf[ni][ks], acc[mi + MH][ni], 0, 0, 0);
    #pragma unroll
    for (int mi = 0; mi < MH; ++mi)
      #pragma unroll
      for (int ni = 0; ni < 2; ++ni)
        #pragma unroll
        for (int ks = 0; ks < 2; ++ks)
          acc[mi + MH][ni] = __builtin_amdgcn_mfma_f32_16x16x32_bf16(ah[mi][ks], bf[ni][ks], acc[mi + MH][ni], 0, 0, 0);
    __builtin_amdgcn_s_setprio(0);

    barrier_nodrain();
    if (t + 2 < NT) stage(cur, t + 2);
  }
}

// ------- QKV GEMM + table-RoPE epilogue: A[4096x2048] @ [Wq;Wk;Wv]^T, N=6144 -------
// RoPE pair (d even, d odd) on lanes (l15, l15^1): shfl_xor(1) gives partner;
// cos/sin from the precomputed table (L2-resident, no transcendentals, no scratch).
// Rotation applied pre-bf16-rounding; math identical to r8's verified epilogue.
__global__ __launch_bounds__(512, 2) void gemm_qkv5(
    const unsigned short* __restrict__ Axb, const unsigned short* __restrict__ Wqkv,
    const float2* __restrict__ tab,
    unsigned short* __restrict__ Qh, unsigned short* __restrict__ Kh,
    unsigned short* __restrict__ Vt)
{
  __shared__ unsigned short As[2 * 2 * 128 * 64];   // 64 KB
  __shared__ unsigned short Bs[2 * 2 * 128 * 64];   // 64 KB
  const int m0 = blockIdx.y * 256, n0g = blockIdx.x * 256;   // no XCD swizzle (r5: +52% FETCH)
  f32x4 acc[8][4];
  #pragma unroll
  for (int i = 0; i < 8; ++i)
    #pragma unroll
    for (int j = 0; j < 4; ++j) acc[i][j] = (f32x4){0.f, 0.f, 0.f, 0.f};

  gemm_2mp<256, 2>(Axb, Wqkv, As, Bs, m0, n0g, threadIdx.x, acc);

  const int tid = threadIdx.x, wave = tid >> 6, lane = tid & 63;
  const int l15 = lane & 15, quad = lane >> 4, wr = wave >> 2, wc = wave & 3;
  const int z = n0g >> 11;                      // 0=Q 1=K 2=V (uniform per block)
  if (z < 2) {
    unsigned short* dst = z ? Kh : Qh;
    #pragma unroll
    for (int mi = 0; mi < 8; ++mi)
      #pragma unroll
      for (int ni = 0; ni < 4; ++ni) {
        int row0 = m0 + mi * 32 + wr * 16 + quad * 4;
        int col  = (n0g + ni * 64 + wc * 16 + l15) & (D_MODEL - 1);
        int h = col >> 7, d = col & (HD - 1);
        int i2 = d >> 1;
        bool ev = (d & 1) == 0;
        #pragma unroll
        for (int r = 0; r < 4; ++r) {
          int m = row0 + r; int bb = m >> 11; int s = m & (SEQ - 1);
          float v  = acc[mi][ni][r];
          float vp = __shfl_xor(v, 1, 64);     // partner (d^1), same row
          float2 t = tab[(s << 6) + i2];       // (cos, sin), L2-resident 1 MB
          float ro = ev ? (v * t.x - vp * t.y) : (vp * t.y + v * t.x);
          dst[((size_t)(bb * NHEAD + h) * SEQ + s) * HD + d] = f2b(ro);
        }
      }
  } else {
    #pragma unroll
    for (int mi = 0; mi < 8; ++mi)
      #pragma unroll
      for (int ni = 0; ni < 4; ++ni) {
        int row0 = m0 + mi * 32 + wr * 16 + quad * 4;
        int col  = (n0g + ni * 64 + wc * 16 + l15) & (D_MODEL - 1);
        int h = col >> 7, d = col & (HD - 1);
        int bb = row0 >> 11; int s = row0 & (SEQ - 1);
        ushort4 pk;
        pk.x = f2b(acc[mi][ni][0]); pk.y = f2b(acc[mi][ni][1]);
        pk.z = f2b(acc[mi][ni][2]); pk.w = f2b(acc[mi][ni][3]);
        *(ushort4*)(Vt + ((size_t)(bb * NHEAD + h) * HD + d) * SEQ + s) = pk;
      }
  }
}

// ---------------- output GEMM: attn_out[4096x2048] @ Wo^T -> fp32 (r1 core) ----------------
__global__ __launch_bounds__(512, 2) void gemm_out2(
    const unsigned short* __restrict__ A, const unsigned short* __restrict__ Wo,
    float* __restrict__ C)
{
  __shared__ unsigned short As[2 * 128 * 64];   // 32 KB
  __shared__ unsigned short Bs[2 * 256 * 64];   // 64 KB
  const int m0 = blockIdx.y * 128, n0 = blockIdx.x * 256;    // no swizzle
  f32x4 acc[4][4];
  #pragma unroll
  for (int i = 0; i < 4; ++i)
    #pragma unroll
    for (int j = 0; j < 4; ++j) acc[i][j] = (f32x4){0.f, 0.f, 0.f, 0.f};

  gemm_pipe<128, 256>(A, Wo, As, Bs, m0, n0, threadIdx.x, acc);

  const int tid = threadIdx.x, wave = tid >> 6, lane = tid & 63;
  const int l15 = lane & 15, quad = lane >> 4, wr = wave >> 2, wc = wave & 3;
  #pragma unroll
  for (int mi = 0; mi < 4; ++mi)
    #pragma unroll
    for (int ni = 0; ni < 4; ++ni) {
      int row0 = m0 + wr * 64 + mi * 16 + quad * 4;
      int col  = n0 + wc * 64 + ni * 16 + l15;
      #pragma unroll
      for (int r = 0; r < 4; ++r)
        C[(size_t)(row0 + r) * D_MODEL + col] = acc[mi][ni][r];
    }
}

// ---------------- flash attention v4 (r7-proven): double-buffered K/V, 1 barrier/iter ----------------
__global__ __launch_bounds__(256) void attn_k2(
    const unsigned short* __restrict__ Qh, const unsigned short* __restrict__ Kh,
    const unsigned short* __restrict__ Vt, unsigned short* __restrict__ Aout)
{
  __shared__ unsigned short Ks[2][64 * 128];    // 32 KB, chunk' = chunk ^ (row&15)
  __shared__ unsigned short Vs[2][128 * 64];    // 32 KB, chunk' = chunk ^ (row&7)
  __shared__ unsigned short sPb[4][16 * 72];    // 9 KB, per-wave P, stride 72
  const int tid = threadIdx.x;
  const int wave = tid >> 6, lane = tid & 63, l15 = lane & 15, quad = lane >> 4;
  const int bh = blockIdx.y;
  const int b = bh >> 4, h = bh & 15;
  const unsigned short* Qb = Qh + (size_t)bh * SEQ * HD;
  const unsigned short* Kb = Kh + (size_t)bh * SEQ * HD;
  const unsigned short* Vb = Vt + (size_t)bh * HD * SEQ;
  unsigned short* pw = &sPb[wave][0];
  const float scl = 0.08838834764831845f * 1.4426950408889634f; // 1/sqrt(128)*log2(e)

  auto stageKV = [&](int bsel, int it) {
    const int k0 = it * 64;
    unsigned short* kd = &Ks[bsel][0];
    unsigned short* vd = &Vs[bsel][0];
    #pragma unroll
    for (int c = 0; c < 4; ++c) {       // K tile: 64 x 128
      int slot = c * 256 + tid;
      int kr = slot >> 4, pch = slot & 15;
      gll16(Kb + (size_t)(k0 + kr) * HD + ((pch ^ (kr & 15)) * 8), kd + slot * 8);
    }
    #pragma unroll
    for (int c = 0; c < 4; ++c) {       // V^T tile: 128 x 64
      int slot = c * 256 + tid;
      int vr = slot >> 3, pch = slot & 7;
      gll16(Vb + (size_t)vr * SEQ + k0 + ((pch ^ (vr & 7)) * 8), vd + slot * 8);
    }
  };

  #pragma unroll
  for (int half = 0; half < 2; ++half) {
    const int tile = half ? (31 - blockIdx.x) : blockIdx.x;
    const int q0w = tile * 64 + wave * 16;
    const int q = q0w + l15;          // this lane's q-row

    short8 qf[4];
    #pragma unroll
    for (int c = 0; c < 4; ++c)
      qf[c] = *(const short8*)(Qb + (size_t)(q0w + l15) * HD + c * 32 + quad * 8);

    f32x4 o[8];                       // O^T: o[dj][r] = O[q][dj*16 + quad*4 + r]
    #pragma unroll
    for (int dj = 0; dj < 8; ++dj) o[dj] = (f32x4){0.f, 0.f, 0.f, 0.f};
    float ms = -1e30f, ls = 0.f;

    const int trips = tile + 1;
    stageKV(0, 0);
    vmwait<0>(); barrier_nodrain();   // tile 0 published

    for (int it = 0; it < trips; ++it) {
      const int cb = it & 1;
      const int k0 = it * 64;
      if (it + 1 < trips) stageKV(cb ^ 1, it + 1);   // prefetch next tile

      const unsigned short* KsB = &Ks[cb][0];
      const unsigned short* VsB = &Vs[cb][0];

      // S^T = K_tile @ Q^T : row = k (quad*4+r), col = q (l15)
      f32x4 st[4];
      #pragma unroll
      for (int ni = 0; ni < 4; ++ni) st[ni] = (f32x4){0.f, 0.f, 0.f, 0.f};
      __builtin_amdgcn_s_setprio(1);
      #pragma unroll
      for (int ni = 0; ni < 4; ++ni) {
        const int rowb = (ni * 16 + l15) * 128;
        #pragma unroll
        for (int c = 0; c < 4; ++c) {
          short8 kf = *(const short8*)(KsB + rowb + (((c * 4 + quad) ^ l15) * 8));
          st[ni] = __builtin_amdgcn_mfma_f32_16x16x32_bf16(kf, qf[c], st[ni], 0, 0, 0);
        }
      }
      __builtin_amdgcn_s_setprio(0);

      // causal mask (only near diagonal)
      if (k0 + 63 > q0w) {
        #pragma unroll
        for (int ni = 0; ni < 4; ++ni)
          #pragma unroll
          for (int r = 0; r < 4; ++r) {
            int k = k0 + ni * 16 + quad * 4 + r;
            if (k > q) st[ni][r] = -1e30f;
          }
      }

      // online softmax: per-lane (q-row l15) + 2 shuffles across quad partners
      float lm = -1e30f;
      #pragma unroll
      for (int ni = 0; ni < 4; ++ni)
        #pragma unroll
        for (int r = 0; r < 4; ++r) lm = fmaxf(lm, st[ni][r]);
      lm = fmaxf(lm, __shfl_xor(lm, 16, 64));
      lm = fmaxf(lm, __shfl_xor(lm, 32, 64));
      float mn = fmaxf(ms, lm);
      float al = exp2f((ms - mn) * scl);
      ms = mn;
      float nm = mn * scl;
      float rs = 0.f;
      #pragma unroll
      for (int ni = 0; ni < 4; ++ni)
        #pragma unroll
        for (int r = 0; r < 4; ++r) {
          float p = exp2f(fmaf(st[ni][r], scl, -nm));
          st[ni][r] = p;
          rs += p;
        }
      rs += __shfl_xor(rs, 16, 64);
      rs += __shfl_xor(rs, 32, 64);
      ls = ls * al + rs;
      #pragma unroll
      for (int dj = 0; dj < 8; ++dj) o[dj] *= al;   // O^T rows all q=l15: al aligned

      // P^T (st) -> wave-private LDS as P[q=l15][k], read back as B-operand
      #pragma unroll
      for (int ni = 0; ni < 4; ++ni) {
        ushort4 pk;
        pk.x = f2b(st[ni][0]); pk.y = f2b(st[ni][1]);
        pk.z = f2b(st[ni][2]); pk.w = f2b(st[ni][3]);
        *(ushort4*)(pw + l15 * 72 + ni * 16 + quad * 4) = pk;
      }
      short8 pf0 = *(const short8*)(pw + l15 * 72 + quad * 8);
      short8 pf1 = *(const short8*)(pw + l15 * 72 + 32 + quad * 8);

      // O^T += V^T_tile @ P^T : mfma(A=vf, B=pf) -> D[m=d-offset][n=q]
      __builtin_amdgcn_s_setprio(1);
      #pragma unroll
      for (int dj = 0; dj < 8; ++dj) {
        const int vrow = (dj * 16 + l15) * 64;
        short8 v0 = *(const short8*)(VsB + vrow + (((quad) ^ (l15 & 7)) * 8));
        short8 v1 = *(const short8*)(VsB + vrow + (((4 + quad) ^ (l15 & 7)) * 8));
        o[dj] = __builtin_amdgcn_mfma_f32_16x16x32_bf16(v0, pf0, o[dj], 0, 0, 0);
        o[dj] = __builtin_amdgcn_mfma_f32_16x16x32_bf16(v1, pf1, o[dj], 0, 0, 0);
      }
      __builtin_amdgcn_s_setprio(0);

      vmwait<0>();          // own next-tile stages landed (issued before compute)
      barrier_nodrain();    // publish all waves' stages; reads of cb complete (WAR)
    }

    // epilogue: o[dj][r] = O[q = q0w+l15][d = dj*16 + quad*4 + r] (unnormalized)
    float rl = 1.0f / ls;
    #pragma unroll
    for (int dj = 0; dj < 8; ++dj) {
      ushort4 pk;
      pk.x = f2b(o[dj][0] * rl); pk.y = f2b(o[dj][1] * rl);
      pk.z = f2b(o[dj][2] * rl); pk.w = f2b(o[dj][3] * rl);
      *(ushort4*)(Aout + ((size_t)(b * SEQ + q)) * D_MODEL + h * HD + dj * 16 + quad * 4) = pk;
    }
  }
}

extern "C" void kernel_launch(void* const* d_in, const int* in_sizes, int n_in,
                              void* d_out, int out_size, void* d_ws, size_t ws_size,
                              hipStream_t stream)
{
  const float* x  = (const float*)d_in[0];
  const float* Wq = (const float*)d_in[1];
  const float* Wk = (const float*)d_in[2];
  const float* Wv = (const float*)d_in[3];
  const float* Wo = (const float*)d_in[4];
  float* out = (float*)d_out;

  unsigned short* xb  = (unsigned short*)d_ws;        // 8M
  unsigned short* wqb = xb  + 8388608;                // 4M each; Wq|Wk|Wv contiguous = stacked [6144][2048]
  unsigned short* wkb = wqb + 4194304;
  unsigned short* wvb = wkb + 4194304;
  unsigned short* wob = wvb + 4194304;
  unsigned short* qh  = wob + 4194304;                // 8M each
  unsigned short* kh  = qh  + 8388608;
  unsigned short* vt  = kh  + 8388608;
  unsigned short* ao  = vt  + 8388608;                // total 112 MB
  float2* tab = (float2*)ao;   // 1 MB RoPE table lives in ao until attn overwrites it

  (void)wkb; (void)wvb;
  cast_all<<<24576, 256, 0, stream>>>(x, Wq, Wk, Wv, Wo, xb);
  tab_k<<<512, 256, 0, stream>>>(tab);
  gemm_qkv5<<<dim3(24, 16), 512, 0, stream>>>(xb, wqb, tab, qh, kh, vt);
  attn_k2<<<dim3(16, 32), 256, 0, stream>>>(qh, kh, vt, ao);
  gemm_out2<<<dim3(8, 32), 512, 0, stream>>>(ao, wob, out);
}